// Round 1
// baseline (104.785 us; speedup 1.0000x reference)
//
#include <hip/hip_runtime.h>

#define HIDDEN 14336
#define NCHUNK 28

// LDS layout: pad +4 floats per 64-float block.
// la(i) = i + (i/64)*4. Total: 14336 + 224*4 = 15232 floats = 60928 B.
static __device__ __forceinline__ int la(int i) { return i + ((i >> 6) << 2); }

// Fixed 28x28 Hadamard sign matrix from the reference (row-major, '+' = +1).
constexpr char HS[28][29] = {
    "++++++++++++++-+++++++++++++",
    "+++-++----++-++-+-++----++-+",
    "++++-++----++-++-+-++----++-",
    "+-+++-++----+++-+-+-++----++",
    "++-+++-++----+++-+-+-++----+",
    "+++-+++-++----+++-+-+-++----",
    "+-++-+++-++---+-++-+-+-++---",
    "+--++-+++-++--+--++-+-+-++--",
    "+---++-+++-++-+---++-+-+-++-",
    "+----++-+++-+++----++-+-+-++",
    "++----++-+++-+++----++-+-+-+",
    "+++----++-+++-+++----++-+-+-",
    "+-++----++-++++-++----++-+-+",
    "++-++----++-++++-++----++-+-",
    "-+++++++++++++--------------",
    "+-+-++----++-+---+--++++--+-",
    "++-+-++----++-----+--++++--+",
    "+-+-+-++----++-+---+--++++--",
    "++-+-+-++----+--+---+--++++-",
    "+++-+-+-++-------+---+--++++",
    "+-++-+-+-++----+--+---+--+++",
    "+--++-+-+-++---++--+---+--++",
    "+---++-+-+-++--+++--+---+--+",
    "+----++-+-+-++-++++--+---+--",
    "++----++-+-+-+--++++--+---+-",
    "+++----++-+-+----++++--+---+",
    "+-++----++-+-+-+--++++--+---",
    "++-++----++-+---+--++++--+--",
};

// In-register 8-point FWHT (stages h=1,2,4 of the local index).
static __device__ __forceinline__ void fwht8(float v[8]) {
    float a0 = v[0] + v[1], a1 = v[0] - v[1];
    float a2 = v[2] + v[3], a3 = v[2] - v[3];
    float a4 = v[4] + v[5], a5 = v[4] - v[5];
    float a6 = v[6] + v[7], a7 = v[6] - v[7];
    float b0 = a0 + a2, b2 = a0 - a2;
    float b1 = a1 + a3, b3 = a1 - a3;
    float b4 = a4 + a6, b6 = a4 - a6;
    float b5 = a5 + a7, b7 = a5 - a7;
    v[0] = b0 + b4; v[4] = b0 - b4;
    v[1] = b1 + b5; v[5] = b1 - b5;
    v[2] = b2 + b6; v[6] = b2 - b6;
    v[3] = b3 + b7; v[7] = b3 - b7;
}

__global__ __launch_bounds__(256) void quarot_kernel(const float* __restrict__ X,
                                                     float* __restrict__ Y) {
    __shared__ float s[15232];
    const int tid = threadIdx.x;
    const size_t row = blockIdx.x;
    const float* __restrict__ xr = X + row * (size_t)HIDDEN;
    float* __restrict__ yr = Y + row * (size_t)HIDDEN;
    const float scale = 1.0f / sqrtf((float)HIDDEN);  // folds at compile time

    // ---- Phase 1: global load (float4 x2) + FWHT8 over stride-1 (h=1,2,4), store to LDS ----
    #pragma unroll
    for (int it = 0; it < 7; ++it) {
        const int a = tid + it * 256;   // 8-float task id, 1792 per row
        const int base = a << 3;
        float v[8];
        const float4 u0 = *reinterpret_cast<const float4*>(xr + base);
        const float4 u1 = *reinterpret_cast<const float4*>(xr + base + 4);
        v[0] = u0.x * scale; v[1] = u0.y * scale; v[2] = u0.z * scale; v[3] = u0.w * scale;
        v[4] = u1.x * scale; v[5] = u1.y * scale; v[6] = u1.z * scale; v[7] = u1.w * scale;
        fwht8(v);
        const int ba = la(base);        // base%8==0 -> both float4 stay in one 64-block
        *reinterpret_cast<float4*>(s + ba)     = make_float4(v[0], v[1], v[2], v[3]);
        *reinterpret_cast<float4*>(s + ba + 4) = make_float4(v[4], v[5], v[6], v[7]);
    }
    __syncthreads();

    // ---- Phase 2: FWHT8 over stride-8 (h=8,16,32) ----
    #pragma unroll
    for (int it = 0; it < 7; ++it) {
        const int id = tid + it * 256;
        const int chunk = id >> 6;
        const int q = id & 63;
        const int base = chunk * 512 + ((q >> 3) << 6) + (q & 7);
        float v[8];
        #pragma unroll
        for (int k = 0; k < 8; ++k) v[k] = s[la(base + (k << 3))];
        fwht8(v);
        #pragma unroll
        for (int k = 0; k < 8; ++k) s[la(base + (k << 3))] = v[k];
    }
    __syncthreads();

    // ---- Phase 3: FWHT8 over stride-64 (h=64,128,256) ----
    #pragma unroll
    for (int it = 0; it < 7; ++it) {
        const int id = tid + it * 256;
        const int chunk = id >> 6;
        const int c = id & 63;
        const int base = chunk * 512 + c;
        float v[8];
        #pragma unroll
        for (int k = 0; k < 8; ++k) v[k] = s[la(base + (k << 6))];
        fwht8(v);
        #pragma unroll
        for (int k = 0; k < 8; ++k) s[la(base + (k << 6))] = v[k];
    }
    __syncthreads();

    // ---- Phase 4: H28 mix across chunks at each column c, store to global ----
    #pragma unroll
    for (int it = 0; it < 2; ++it) {
        const int c = tid + it * 256;
        float x[28];
        #pragma unroll
        for (int j = 0; j < NCHUNK; ++j) x[j] = s[la(j * 512 + c)];
        #pragma unroll
        for (int i = 0; i < NCHUNK; ++i) {
            // 4 interleaved partial sums to break the fp-add dependency chain
            float p0 = (HS[i][0] == '+') ? x[0] : -x[0];
            float p1 = (HS[i][1] == '+') ? x[1] : -x[1];
            float p2 = (HS[i][2] == '+') ? x[2] : -x[2];
            float p3 = (HS[i][3] == '+') ? x[3] : -x[3];
            #pragma unroll
            for (int j = 4; j < NCHUNK; j += 4) {
                p0 = (HS[i][j + 0] == '+') ? p0 + x[j + 0] : p0 - x[j + 0];
                p1 = (HS[i][j + 1] == '+') ? p1 + x[j + 1] : p1 - x[j + 1];
                p2 = (HS[i][j + 2] == '+') ? p2 + x[j + 2] : p2 - x[j + 2];
                p3 = (HS[i][j + 3] == '+') ? p3 + x[j + 3] : p3 - x[j + 3];
            }
            yr[i * 512 + c] = (p0 + p1) + (p2 + p3);
        }
    }
}

extern "C" void kernel_launch(void* const* d_in, const int* in_sizes, int n_in,
                              void* d_out, int out_size, void* d_ws, size_t ws_size,
                              hipStream_t stream) {
    const float* X = (const float*)d_in[0];
    float* Y = (float*)d_out;
    const int rows = in_sizes[0] / HIDDEN;  // 4096
    quarot_kernel<<<dim3(rows), dim3(256), 0, stream>>>(X, Y);
}

// Round 2
// 93.058 us; speedup vs baseline: 1.1260x; 1.1260x over previous
//
#include <hip/hip_runtime.h>

#define HIDDEN 14336
#define NCHUNK 28

// LDS layout: pad +4 floats per 64-float block.
// la(i) = i + (i/64)*4. Total: 14336 + 224*4 = 15232 floats = 60928 B.
static __device__ __forceinline__ int la(int i) { return i + ((i >> 6) << 2); }

// Fixed 28x28 Hadamard sign matrix from the reference (row-major, '+' = +1).
// Structure (verified): H28 = [[C+I, C-I],[C-I, -(C+I)]], C = 14x14 zero-diag
// conference matrix, C[i][j] = HS[i][j] for i,j<14, i!=j.
constexpr char HS[28][29] = {
    "++++++++++++++-+++++++++++++",
    "+++-++----++-++-+-++----++-+",
    "++++-++----++-++-+-++----++-",
    "+-+++-++----+++-+-+-++----++",
    "++-+++-++----+++-+-+-++----+",
    "+++-+++-++----+++-+-+-++----",
    "+-++-+++-++---+-++-+-+-++---",
    "+--++-+++-++--+--++-+-+-++--",
    "+---++-+++-++-+---++-+-+-++-",
    "+----++-+++-+++----++-+-+-++",
    "++----++-+++-+++----++-+-+-+",
    "+++----++-+++-+++----++-+-+-",
    "+-++----++-++++-++----++-+-+",
    "++-++----++-++++-++----++-+-",
    "-+++++++++++++--------------",
    "+-+-++----++-+---+--++++--+-",
    "++-+-++----++-----+--++++--+",
    "+-+-+-++----++-+---+--++++--",
    "++-+-+-++----+--+---+--++++-",
    "+++-+-+-++-------+---+--++++",
    "+-++-+-+-++----+--+---+--+++",
    "+--++-+-+-++---++--+---+--++",
    "+---++-+-+-++--+++--+---+--+",
    "+----++-+-+-++-++++--+---+--",
    "++----++-+-+-+--++++--+---+-",
    "+++----++-+-+----++++--+---+",
    "+-++----++-+-+-+--++++--+---",
    "++-++----++-+---+--++++--+--",
};

// In-register 8-point FWHT (stages h=1,2,4 of the local index).
static __device__ __forceinline__ void fwht8(float v[8]) {
    float a0 = v[0] + v[1], a1 = v[0] - v[1];
    float a2 = v[2] + v[3], a3 = v[2] - v[3];
    float a4 = v[4] + v[5], a5 = v[4] - v[5];
    float a6 = v[6] + v[7], a7 = v[6] - v[7];
    float b0 = a0 + a2, b2 = a0 - a2;
    float b1 = a1 + a3, b3 = a1 - a3;
    float b4 = a4 + a6, b6 = a4 - a6;
    float b5 = a5 + a7, b7 = a5 - a7;
    v[0] = b0 + b4; v[4] = b0 - b4;
    v[1] = b1 + b5; v[5] = b1 - b5;
    v[2] = b2 + b6; v[6] = b2 - b6;
    v[3] = b3 + b7; v[7] = b3 - b7;
}

static __device__ __forceinline__ float2 f2add(float2 a, float2 b) {
    return make_float2(a.x + b.x, a.y + b.y);
}
static __device__ __forceinline__ float2 f2sub(float2 a, float2 b) {
    return make_float2(a.x - b.x, a.y - b.y);
}
static __device__ __forceinline__ float2 f2fma(float k, float2 a, float2 b) {
    return make_float2(fmaf(k, a.x, b.x), fmaf(k, a.y, b.y));
}

__global__ __launch_bounds__(256) void quarot_kernel(const float* __restrict__ X,
                                                     float* __restrict__ Y) {
    __shared__ float s[15232];
    const int tid = threadIdx.x;
    const size_t row = blockIdx.x;
    const float* __restrict__ xr = X + row * (size_t)HIDDEN;
    float* __restrict__ yr = Y + row * (size_t)HIDDEN;
    const float scale = 1.0f / sqrtf((float)HIDDEN);  // folds at compile time

    // ---- Phase 1: global load (float4 x2) + FWHT8 over stride-1 (h=1,2,4), store to LDS ----
    #pragma unroll
    for (int it = 0; it < 7; ++it) {
        const int a = tid + it * 256;   // 8-float task id, 1792 per row
        const int base = a << 3;
        float v[8];
        const float4 u0 = *reinterpret_cast<const float4*>(xr + base);
        const float4 u1 = *reinterpret_cast<const float4*>(xr + base + 4);
        v[0] = u0.x * scale; v[1] = u0.y * scale; v[2] = u0.z * scale; v[3] = u0.w * scale;
        v[4] = u1.x * scale; v[5] = u1.y * scale; v[6] = u1.z * scale; v[7] = u1.w * scale;
        fwht8(v);
        const int ba = la(base);        // base%8==0 -> both float4 stay in one 64-block
        *reinterpret_cast<float4*>(s + ba)     = make_float4(v[0], v[1], v[2], v[3]);
        *reinterpret_cast<float4*>(s + ba + 4) = make_float4(v[4], v[5], v[6], v[7]);
    }
    __syncthreads();

    // ---- Phase 2: FWHT8 over stride-8 (h=8,16,32) ----
    #pragma unroll
    for (int it = 0; it < 7; ++it) {
        const int id = tid + it * 256;
        const int chunk = id >> 6;
        const int q = id & 63;
        const int base = chunk * 512 + ((q >> 3) << 6) + (q & 7);
        float v[8];
        #pragma unroll
        for (int k = 0; k < 8; ++k) v[k] = s[la(base + (k << 3))];
        fwht8(v);
        #pragma unroll
        for (int k = 0; k < 8; ++k) s[la(base + (k << 3))] = v[k];
    }
    __syncthreads();

    // ---- Phase 3: FWHT8 over stride-64 (h=64,128,256) ----
    #pragma unroll
    for (int it = 0; it < 7; ++it) {
        const int id = tid + it * 256;
        const int chunk = id >> 6;
        const int c = id & 63;
        const int base = chunk * 512 + c;
        float v[8];
        #pragma unroll
        for (int k = 0; k < 8; ++k) v[k] = s[la(base + (k << 6))];
        fwht8(v);
        #pragma unroll
        for (int k = 0; k < 8; ++k) s[la(base + (k << 6))] = v[k];
    }
    __syncthreads();

    // ---- Phase 4: H28 mix via conference-matrix CSE, column pairs, store ----
    // y_top = C*u + d, y_bot = C*d - u  where u = x1+x2, d = x1-x2,
    // and (C*v)_i = (Sv - v_i) - 2 * sum_{j in neg_i} v_j.
    {
        const int c = tid << 1;
        float2 u[14], d[14];
        #pragma unroll
        for (int j = 0; j < 14; ++j) {
            const float2 a = *reinterpret_cast<const float2*>(s + la(j * 512 + c));
            const float2 b = *reinterpret_cast<const float2*>(s + la((j + 14) * 512 + c));
            u[j] = f2add(a, b);
            d[j] = f2sub(a, b);
        }
        // Pairwise-tree totals (short dependency chains)
        float2 su0 = f2add(f2add(u[0], u[1]), f2add(u[2], u[3]));
        float2 su1 = f2add(f2add(u[4], u[5]), f2add(u[6], u[7]));
        float2 su2 = f2add(f2add(u[8], u[9]), f2add(u[10], u[11]));
        float2 su3 = f2add(u[12], u[13]);
        const float2 Su = f2add(f2add(su0, su1), f2add(su2, su3));
        float2 sd0 = f2add(f2add(d[0], d[1]), f2add(d[2], d[3]));
        float2 sd1 = f2add(f2add(d[4], d[5]), f2add(d[6], d[7]));
        float2 sd2 = f2add(f2add(d[8], d[9]), f2add(d[10], d[11]));
        float2 sd3 = f2add(d[12], d[13]);
        const float2 Sd = f2add(f2add(sd0, sd1), f2add(sd2, sd3));

        #pragma unroll
        for (int i = 0; i < 14; ++i) {
            float2 nu = make_float2(0.0f, 0.0f);
            float2 nd = make_float2(0.0f, 0.0f);
            #pragma unroll
            for (int j = 0; j < 14; ++j) {
                if (j != i && HS[i][j] == '-') {   // compile-time folded
                    nu = f2add(nu, u[j]);
                    nd = f2add(nd, d[j]);
                }
            }
            const float2 Cu = f2fma(-2.0f, nu, f2sub(Su, u[i]));
            const float2 Cd = f2fma(-2.0f, nd, f2sub(Sd, d[i]));
            const float2 yt = f2add(Cu, d[i]);
            const float2 yb = f2sub(Cd, u[i]);
            *reinterpret_cast<float2*>(yr + i * 512 + c) = yt;
            *reinterpret_cast<float2*>(yr + (i + 14) * 512 + c) = yb;
        }
    }
}

extern "C" void kernel_launch(void* const* d_in, const int* in_sizes, int n_in,
                              void* d_out, int out_size, void* d_ws, size_t ws_size,
                              hipStream_t stream) {
    const float* X = (const float*)d_in[0];
    float* Y = (float*)d_out;
    const int rows = in_sizes[0] / HIDDEN;  // 4096
    quarot_kernel<<<dim3(rows), dim3(256), 0, stream>>>(X, Y);
}